// Round 6
// baseline (365.898 us; speedup 1.0000x reference)
//
#include <hip/hip_runtime.h>

// Problem constants
#define B_  16
#define S_  1024
#define IN_ 1024
#define H_  1024
#define N1  (2*H_)          // 2048 output cols of GEMM1
#define M1  (B_*S_)         // 16384 rows of GEMM1
#define K1  IN_             // 1024
#define XN  (M1*IN_)        // 16,777,216 elems of x
#define WN  (N1*IN_)        //  2,097,152 elems of W

// Core: 128m x 256n tile, 8 waves (2x4 of 64x64), 32 phases of K=32,
// ring of 3 LDS slots (slot = A[128][32] + B[256][32] bf16 = 24 KiB = 72 KiB
// total -> 2 blocks/CU), stage 2 phases ahead, counted vmcnt(3).
#define BMr  128
#define BNr  256
#define SLOT 12288          // shorts per ring slot (A 4096 + B 8192)
#define RING 36864          // 3 slots (72 KiB)
#define CPP  264            // epilogue transpose LDS stride (shorts)

typedef __attribute__((ext_vector_type(8))) short  short8;   // 8 bf16 (MFMA A/B frag)
typedef __attribute__((ext_vector_type(4))) float  floatx4;  // MFMA C/D frag

// fp32 -> bf16 round-to-nearest-even
__device__ __forceinline__ unsigned short f2bf(float f) {
    unsigned int u = __float_as_uint(f);
    u += 0x7fffu + ((u >> 16) & 1u);
    return (unsigned short)(u >> 16);
}

// async global->LDS, 16 B per lane; LDS dst is wave-uniform base + lane*16
#define GLDS16(gp, lp) __builtin_amdgcn_global_load_lds(                      \
    (const __attribute__((address_space(1))) void*)(gp),                      \
    (__attribute__((address_space(3))) void*)(lp), 16, 0, 0)

// ---------------------------------------------------------------------------
// convert: fp32 -> bf16 for x and W (memory-bound).
// ---------------------------------------------------------------------------
__global__ __launch_bounds__(256) void convert_kernel(
    const float* __restrict__ x, const float* __restrict__ W,
    unsigned short* __restrict__ xb, unsigned short* __restrict__ Wb)
{
    size_t i = ((size_t)blockIdx.x * 256 + threadIdx.x) * 8;
    const float* src;
    unsigned short* dst;
    if (i < (size_t)XN) { src = x + i; dst = xb + i; }
    else                { src = W + (i - XN); dst = Wb + (i - XN); }
    float4 a = *(const float4*)(src);
    float4 b = *(const float4*)(src + 4);
    ushort4 p = { f2bf(a.x), f2bf(a.y), f2bf(a.z), f2bf(a.w) };
    ushort4 q = { f2bf(b.x), f2bf(b.y), f2bf(b.z), f2bf(b.w) };
    *(ushort4*)(dst)     = p;
    *(ushort4*)(dst + 4) = q;
}

// ---------------------------------------------------------------------------
// Stage one K=32 phase (k-cols [kt,kt+32)) into a ring slot. 3 glds/thread.
// Swizzle on GLOBAL source: phys chunk p at row holds logical c = p^(row&3);
// LDS dest linear (global_load_lds constraint).
// ---------------------------------------------------------------------------
__device__ __forceinline__ void stage_ph(
    const unsigned short* Ag, const unsigned short* Bg,
    unsigned short* slot, int kt, int wave, int lane)
{
    {   // A[128][32]: 512 chunks, 1/thread
        int e   = wave * 64 + lane;
        int row = e >> 2, p = e & 3, c = p ^ (row & 3);
        GLDS16(Ag + (size_t)row * 1024 + kt + c * 8, slot + (size_t)e * 8);
    }
#pragma unroll
    for (int h = 0; h < 2; ++h) {  // B[256][32]: 1024 chunks, 2/thread
        int e   = wave * 128 + h * 64 + lane;
        int row = e >> 2, p = e & 3, c = p ^ (row & 3);
        GLDS16(Bg + (size_t)row * 1024 + kt + c * 8, slot + 4096 + (size_t)e * 8);
    }
}

// ---------------------------------------------------------------------------
// K-loop: 32 phases of K=32. Phase p: [vmcnt(3) barrier] stage(p+2) ->
// read 8 frags -> 16 MFMA. The newest stage (3 loads) stays in flight across
// every barrier; never drains to 0 mid-loop. Ring slot (p+2)%3 was consumed
// in phase p-1 (pre-barrier) -> safe to overwrite.
// ---------------------------------------------------------------------------
__device__ __forceinline__ void gemm_core(
    const unsigned short* Ag, const unsigned short* Bg,
    unsigned short* lds, floatx4 (&acc)[4][4], int wave, int lane)
{
    const int quad = lane >> 4, r = lane & 15;
    const int wmw  = (wave >> 2) * 64;            // 2 wave-rows x 4 wave-cols
    const int wnw  = (wave & 3) * 64;
    const int sw   = (quad ^ (r & 3)) * 8;

    stage_ph(Ag, Bg, lds,         0, wave, lane);
    stage_ph(Ag, Bg, lds + SLOT, 32, wave, lane);

    unsigned short* slot_c = lds;                 // slot of phase p
    unsigned short* slot_s = lds + 2 * SLOT;      // stage target (p+2)
    for (int p = 0; p < 32; ++p) {
        if (p < 31) asm volatile("s_waitcnt vmcnt(3)" ::: "memory");
        else        asm volatile("s_waitcnt vmcnt(0)" ::: "memory");
        __builtin_amdgcn_s_barrier();
        __builtin_amdgcn_sched_barrier(0);
        if (p < 30) stage_ph(Ag, Bg, slot_s, (p + 2) * 32, wave, lane);
        short8 fa[4], fb[4];
#pragma unroll
        for (int i = 0; i < 4; ++i)
            fa[i] = *(const short8*)(slot_c + (wmw + i * 16 + r) * 32 + sw);
#pragma unroll
        for (int j = 0; j < 4; ++j)
            fb[j] = *(const short8*)(slot_c + 4096 + (wnw + j * 16 + r) * 32 + sw);
        __builtin_amdgcn_s_setprio(1);
#pragma unroll
        for (int i = 0; i < 4; ++i)
#pragma unroll
            for (int j = 0; j < 4; ++j)
                acc[i][j] = __builtin_amdgcn_mfma_f32_16x16x32_bf16(
                    fa[i], fb[j], acc[i][j], 0, 0, 0);
        __builtin_amdgcn_s_setprio(0);
        __builtin_amdgcn_sched_barrier(0);
        slot_c += SLOT; if (slot_c == lds + RING) slot_c = lds;
        slot_s += SLOT; if (slot_s == lds + RING) slot_s = lds;
    }
    __syncthreads();                              // LDS reusable by epilogue
}

// ---------------------------------------------------------------------------
// GEMM1: C[m,n] = sum_k xb[m,k]*Wb[n,k]; relu -> fp32 keys/vals to d_out and
// bf16 transposed keysT/valsT to ws. 1024 blocks (128 mt x 8 nt), 2 rounds
// of 2 blocks/CU; XCD x owns m-stripe [16x,16x+16).
// ---------------------------------------------------------------------------
__global__ __launch_bounds__(512, 4) void gemm1_kernel(
    const unsigned short* __restrict__ xb, const unsigned short* __restrict__ Wb,
    float* __restrict__ out,
    unsigned short* __restrict__ kT, unsigned short* __restrict__ vT)
{
    __shared__ unsigned short lds[RING];          // 72 KiB -> 2 blocks/CU

    const int tid  = threadIdx.x;
    const int wave = tid >> 6, lane = tid & 63;
    const int quad = lane >> 4, r = lane & 15;
    const int wmw  = (wave >> 2) * 64;
    const int wnw  = (wave & 3) * 64;

    const int L   = blockIdx.x;
    const int xcd = L & 7, s = L >> 3;            // s: 0..127
    const int mt  = xcd * 16 + (s >> 3);          // 0..127
    const int nt  = s & 7;                        // 0..7
    const int m0  = mt * BMr, n0 = nt * BNr;

    const unsigned short* Ag = xb + (size_t)m0 * K1;
    const unsigned short* Bg = Wb + (size_t)n0 * K1;

    floatx4 acc[4][4] = {};
    gemm_core(Ag, Bg, lds, acc, wave, lane);

    const bool isKeys = (nt < 4);
    float* outKV    = out + (isKeys ? (size_t)M1 * H_ : (size_t)2 * M1 * H_);
    const int ncol0 = isKeys ? n0 : (n0 - 1024);

    // fp32 relu writes (each wave its own 64x64 region)
#pragma unroll
    for (int i = 0; i < 4; ++i)
#pragma unroll
        for (int j = 0; j < 4; ++j)
#pragma unroll
            for (int d = 0; d < 4; ++d) {
                int row_l = wmw + i * 16 + quad * 4 + d;
                int col_l = wnw + j * 16 + r;
                outKV[(size_t)(m0 + row_l) * H_ + ncol0 + col_l] =
                    fmaxf(acc[i][j][d], 0.0f);
            }

    // bf16 transposed writes via LDS (single pass: 128 x 264 shorts = 66 KiB)
#pragma unroll
    for (int i = 0; i < 4; ++i)
#pragma unroll
        for (int j = 0; j < 4; ++j)
#pragma unroll
            for (int d = 0; d < 4; ++d) {
                int row_l = wmw + i * 16 + quad * 4 + d;    // 0..127
                int col_l = wnw + j * 16 + r;               // 0..255
                lds[row_l * CPP + col_l] = f2bf(fmaxf(acc[i][j][d], 0.0f));
            }
    __syncthreads();

    unsigned short* wsT = isKeys ? kT : vT;
    const int b  = m0 >> 10;
    const int s0 = m0 & 1023;
    unsigned short* dstB = wsT + (size_t)b * H_ * S_ + (size_t)ncol0 * S_ + s0;
#pragma unroll
    for (int it = 0; it < 16; ++it) {
        int o   = it * 512 + tid;                 // 0..8191
        int n_l = o >> 5;                         // 0..255
        int m4  = (o & 31) * 4;                   // 0..124
        ushort4 v;
        v.x = lds[(m4 + 0) * CPP + n_l];
        v.y = lds[(m4 + 1) * CPP + n_l];
        v.z = lds[(m4 + 2) * CPP + n_l];
        v.w = lds[(m4 + 3) * CPP + n_l];
        *(ushort4*)(dstB + (size_t)n_l * S_ + m4) = v;
    }
}

// ---------------------------------------------------------------------------
// GEMM2 (batched): mem[b][m,n] = sum_t kT[b][m,t]*vT[b][n,t].
// 512 blocks (16 batches x 8 mt x 4 nt), 1 round of 2 blocks/CU;
// XCD x owns batches {2x,2x+1} (working set L2-friendly).
// ---------------------------------------------------------------------------
__global__ __launch_bounds__(512, 4) void gemm2_kernel(
    const unsigned short* __restrict__ kT, const unsigned short* __restrict__ vT,
    float* __restrict__ mem)
{
    __shared__ unsigned short lds[RING];          // 72 KiB -> 2 blocks/CU

    const int tid  = threadIdx.x;
    const int wave = tid >> 6, lane = tid & 63;
    const int quad = lane >> 4, r = lane & 15;
    const int wmw  = (wave >> 2) * 64;
    const int wnw  = (wave & 3) * 64;

    const int L   = blockIdx.x;
    const int xcd = L & 7, s = L >> 3;            // s: 0..63
    const int b   = xcd * 2 + (s >> 5);           // batch 0..15
    const int tt  = s & 31;
    const int m0  = (tt >> 2) * BMr;              // 8 m-tiles of 128
    const int n0  = (tt & 3) * BNr;               // 4 n-tiles of 256

    const unsigned short* Ag = kT + (size_t)b * H_ * S_ + (size_t)m0 * S_;
    const unsigned short* Bg = vT + (size_t)b * H_ * S_ + (size_t)n0 * S_;

    floatx4 acc[4][4] = {};
    gemm_core(Ag, Bg, lds, acc, wave, lane);

    float* outb = mem + (size_t)b * H_ * H_;
#pragma unroll
    for (int i = 0; i < 4; ++i)
#pragma unroll
        for (int j = 0; j < 4; ++j)
#pragma unroll
            for (int d = 0; d < 4; ++d) {
                int row_l = wmw + i * 16 + quad * 4 + d;
                int col_l = wnw + j * 16 + r;
                outb[(size_t)(m0 + row_l) * H_ + n0 + col_l] = acc[i][j][d];
            }
}

extern "C" void kernel_launch(void* const* d_in, const int* in_sizes, int n_in,
                              void* d_out, int out_size, void* d_ws, size_t ws_size,
                              hipStream_t stream) {
    const float* x = (const float*)d_in[0];   // [16,1024,1024] f32
    const float* W = (const float*)d_in[1];   // [2048,1024] f32
    float* out = (float*)d_out;               // mem(16M) | keys(16M) | vals(16M) f32

    // Stash bf16 inputs in d_out's mem region (not written until gemm2)
    unsigned short* xb = (unsigned short*)d_out;            // 33.5 MB
    unsigned short* Wb = xb + (size_t)XN;                   //  4.2 MB (total 37.7 < 64 MB)

    // ws: keysT/valsT bf16 [B][H][S] (64 MB)
    unsigned short* kT = (unsigned short*)d_ws;
    unsigned short* vT = kT + (size_t)B_ * H_ * S_;

    convert_kernel<<<dim3((XN + WN) / 2048), dim3(256), 0, stream>>>(x, W, xb, Wb);

    gemm1_kernel<<<dim3(1024), dim3(512), 0, stream>>>(xb, Wb, out, kT, vT);

    gemm2_kernel<<<dim3(512), dim3(512), 0, stream>>>(kT, vT, out);
}

// Round 8
// 357.175 us; speedup vs baseline: 1.0244x; 1.0244x over previous
//
#include <hip/hip_runtime.h>

// Problem constants
#define B_  16
#define S_  1024
#define IN_ 1024
#define H_  1024
#define N1  (2*H_)          // 2048 output cols of GEMM1
#define M1  (B_*S_)         // 16384 rows of GEMM1
#define K1  IN_             // 1024
#define XN  (M1*IN_)        // 16,777,216 elems of x
#define WN  (N1*IN_)        //  2,097,152 elems of W

// 256x256x64 8-wave tile, double-buffered split-K LDS, faithful 8-phase
// schedule: per phase {stage 1 unit -> [vmcnt(6) at k-half boundary] ->
// s_barrier -> 4/8 ds_read_b128 -> lgkmcnt(0) -> setprio(1) 16 MFMA
// setprio(0) -> s_barrier}. vmcnt never drains to 0 until the peeled tail.
#define BM  256
#define BN  256
#define BK  64
#define CP  257             // epilogue transpose LDS stride (odd -> conflict-free)

// LDS (shorts): per dbuf = A[kh=0][256][32] A[kh=1][256][32]
//                          B[kh=0][256][32] B[kh=1][256][32]  (64 KiB)
#define USZ  8192
#define ASZ  16384
#define TBUF 32768

typedef __attribute__((ext_vector_type(8))) short  short8;   // 8 bf16 (MFMA A/B frag)
typedef __attribute__((ext_vector_type(4))) float  floatx4;  // MFMA C/D frag

// fp32 -> bf16 round-to-nearest-even
__device__ __forceinline__ unsigned short f2bf(float f) {
    unsigned int u = __float_as_uint(f);
    u += 0x7fffu + ((u >> 16) & 1u);
    return (unsigned short)(u >> 16);
}

// async global->LDS, 16 B per lane; LDS dst is wave-uniform base + lane*16
#define GLDS16(gp, lp) __builtin_amdgcn_global_load_lds(                      \
    (const __attribute__((address_space(1))) void*)(gp),                      \
    (__attribute__((address_space(3))) void*)(lp), 16, 0, 0)

#define OPEN_VM6 { asm volatile("s_waitcnt vmcnt(6)" ::: "memory");           \
                   __builtin_amdgcn_s_barrier();                              \
                   __builtin_amdgcn_sched_barrier(0); }
#define OPEN_VM4 { asm volatile("s_waitcnt vmcnt(4)" ::: "memory");           \
                   __builtin_amdgcn_s_barrier();                              \
                   __builtin_amdgcn_sched_barrier(0); }
#define OPEN_VM0 { asm volatile("s_waitcnt vmcnt(0)" ::: "memory");           \
                   __builtin_amdgcn_s_barrier();                              \
                   __builtin_amdgcn_sched_barrier(0); }
#define OPEN_BAR { __builtin_amdgcn_s_barrier();                              \
                   __builtin_amdgcn_sched_barrier(0); }
#define CLOSE_BAR { __builtin_amdgcn_sched_barrier(0);                        \
                    __builtin_amdgcn_s_barrier(); }
#define LGKM0 { asm volatile("s_waitcnt lgkmcnt(0)" ::: "memory");            \
                __builtin_amdgcn_sched_barrier(0); }

// ---------------------------------------------------------------------------
// convert: fp32 -> bf16 for x and W (memory-bound).
// ---------------------------------------------------------------------------
__global__ __launch_bounds__(256) void convert_kernel(
    const float* __restrict__ x, const float* __restrict__ W,
    unsigned short* __restrict__ xb, unsigned short* __restrict__ Wb)
{
    size_t i = ((size_t)blockIdx.x * 256 + threadIdx.x) * 8;
    const float* src;
    unsigned short* dst;
    if (i < (size_t)XN) { src = x + i; dst = xb + i; }
    else                { src = W + (i - XN); dst = Wb + (i - XN); }
    float4 a = *(const float4*)(src);
    float4 b = *(const float4*)(src + 4);
    ushort4 p = { f2bf(a.x), f2bf(a.y), f2bf(a.z), f2bf(a.w) };
    ushort4 q = { f2bf(b.x), f2bf(b.y), f2bf(b.z), f2bf(b.w) };
    *(ushort4*)(dst)     = p;
    *(ushort4*)(dst + 4) = q;
}

// ---------------------------------------------------------------------------
// Stage one 16 KiB unit (op: 0=A 1=B, kh: k-half) of K-tile at kt into buf.
// Swizzle on GLOBAL source: phys chunk p at row holds logical c = p^(row&3);
// LDS dest linear (global_load_lds constraint). 2 glds/thread.
// ---------------------------------------------------------------------------
__device__ __forceinline__ void stage_u(
    const unsigned short* Ag, const unsigned short* Bg,
    unsigned short* buf, int op, int kh, int kt, int wave, int lane)
{
    const unsigned short* src = op ? Bg : Ag;
    unsigned short* dst = buf + op * ASZ + kh * USZ;
#pragma unroll
    for (int h = 0; h < 2; ++h) {
        int e   = (wave * 2 + h) * 64 + lane;     // chunk id 0..1023 in unit
        int row = e >> 2, p = e & 3;
        int c   = p ^ (row & 3);
        GLDS16(src + (size_t)row * 1024 + kt + kh * 32 + c * 8,
               dst + (wave * 2 + h) * 512);
    }
}

// ---------------------------------------------------------------------------
// 8-phase K-loop core. Wave tile 128x64 (8 waves: 2 wave-rows x 4 wave-cols).
// Phase (T, q): q=(kh<<1)|mh. B frags read at mh==0, reused at mh==1.
// Reader slot = quad^(r&3): uniform 8 lanes/16B slot = b128 floor.
// ---------------------------------------------------------------------------
__device__ __forceinline__ void gemm_core(
    const unsigned short* Ag, const unsigned short* Bg,
    unsigned short* lds, floatx4 (&acc)[8][4], int wave, int lane)
{
    const int quad = lane >> 4, r = lane & 15;
    const int wmw  = (wave >> 2) * 128;
    const int wnw  = (wave & 3) * 64;
    const int sw   = (quad ^ (r & 3)) * 8;

    short8 af[4], bfr[4];

#define READ_B(cur_, kh_)                                                     \
    _Pragma("unroll") for (int j = 0; j < 4; ++j)                             \
        bfr[j] = *(const short8*)((cur_) + ASZ + (kh_) * USZ                  \
                                  + (wnw + j * 16 + r) * 32 + sw);
#define READ_A(cur_, kh_, mh_)                                                \
    _Pragma("unroll") for (int i = 0; i < 4; ++i)                             \
        af[i] = *(const short8*)((cur_) + (kh_) * USZ                         \
                                 + (wmw + ((mh_) * 4 + i) * 16 + r) * 32 + sw);
#define MFMA16(mh_)                                                           \
    __builtin_amdgcn_s_setprio(1);                                            \
    _Pragma("unroll") for (int i = 0; i < 4; ++i)                             \
        _Pragma("unroll") for (int j = 0; j < 4; ++j)                         \
            acc[(mh_) * 4 + i][j] = __builtin_amdgcn_mfma_f32_16x16x32_bf16(  \
                af[i], bfr[j], acc[(mh_) * 4 + i][j], 0, 0, 0);               \
    __builtin_amdgcn_s_setprio(0);

    // Prologue: tile 0 only (8 glds); tile T+1 staged during tile T.
    stage_u(Ag, Bg, lds, 0, 0, 0, wave, lane);
    stage_u(Ag, Bg, lds, 1, 0, 0, wave, lane);
    stage_u(Ag, Bg, lds, 0, 1, 0, wave, lane);
    stage_u(Ag, Bg, lds, 1, 1, 0, wave, lane);

    for (int T = 0; T < 15; ++T) {
        unsigned short* cur = lds + (T & 1) * TBUF;
        unsigned short* nxt = lds + ((T + 1) & 1) * TBUF;
        const int ktn = (T + 1) * BK;
        // q=0: kh=0, mh=0   (vmcnt(6): drain tile T k0-units, keep 6 newer)
        stage_u(Ag, Bg, nxt, 0, 0, ktn, wave, lane);
        OPEN_VM6
        READ_B(cur, 0) READ_A(cur, 0, 0)
        LGKM0
        MFMA16(0)
        CLOSE_BAR
        // q=1: kh=0, mh=1
        stage_u(Ag, Bg, nxt, 1, 0, ktn, wave, lane);
        OPEN_BAR
        READ_A(cur, 0, 1)
        LGKM0
        MFMA16(1)
        CLOSE_BAR
        // q=2: kh=1, mh=0   (vmcnt(6): drain tile T k1-units)
        stage_u(Ag, Bg, nxt, 0, 1, ktn, wave, lane);
        OPEN_VM6
        READ_B(cur, 1) READ_A(cur, 1, 0)
        LGKM0
        MFMA16(0)
        CLOSE_BAR
        // q=3: kh=1, mh=1
        stage_u(Ag, Bg, nxt, 1, 1, ktn, wave, lane);
        OPEN_BAR
        READ_A(cur, 1, 1)
        LGKM0
        MFMA16(1)
        CLOSE_BAR
    }
    {   // Peeled tile 15: no staging; drain 4 -> 0.
        unsigned short* cur = lds + TBUF;
        OPEN_VM4
        READ_B(cur, 0) READ_A(cur, 0, 0)
        LGKM0
        MFMA16(0)
        CLOSE_BAR
        OPEN_BAR
        READ_A(cur, 0, 1)
        LGKM0
        MFMA16(1)
        CLOSE_BAR
        OPEN_VM0
        READ_B(cur, 1) READ_A(cur, 1, 0)
        LGKM0
        MFMA16(0)
        CLOSE_BAR
        OPEN_BAR
        READ_A(cur, 1, 1)
        LGKM0
        MFMA16(1)
    }
    __syncthreads();                              // LDS reusable by epilogue
#undef READ_B
#undef READ_A
#undef MFMA16
}

// ---------------------------------------------------------------------------
// GEMM1: C[m,n] = sum_k xb[m,k]*Wb[n,k]; relu -> fp32 keys/vals to d_out and
// bf16 transposed keysT/valsT to ws. 512 blocks; XCD x owns m-stripe
// [8x,8x+8) x all 8 n-tiles.
// ---------------------------------------------------------------------------
__global__ __launch_bounds__(512, 2) void gemm1_kernel(
    const unsigned short* __restrict__ xb, const unsigned short* __restrict__ Wb,
    float* __restrict__ out,
    unsigned short* __restrict__ kT, unsigned short* __restrict__ vT)
{
    __shared__ unsigned short lds[65536];         // 128 KiB

    const int tid  = threadIdx.x;
    const int wave = tid >> 6, lane = tid & 63;
    const int quad = lane >> 4, r = lane & 15;
    const int wmw  = (wave >> 2) * 128;
    const int wnw  = (wave & 3) * 64;

    const int L   = blockIdx.x;
    const int xcd = L & 7, s = L >> 3;            // s: 0..63
    const int mt  = xcd * 8 + (s >> 3);           // 0..63
    const int nt  = s & 7;                        // 0..7
    const int m0  = mt * BM, n0 = nt * BN;

    const unsigned short* Ag = xb + (size_t)m0 * K1;
    const unsigned short* Bg = Wb + (size_t)n0 * K1;

    floatx4 acc[8][4] = {};
    gemm_core(Ag, Bg, lds, acc, wave, lane);

    const bool isKeys = (nt < 4);
    float* outKV    = out + (isKeys ? (size_t)M1 * H_ : (size_t)2 * M1 * H_);
    const int ncol0 = isKeys ? n0 : (n0 - 1024);

    // fp32 relu writes (each wave its own 128x64 region)
#pragma unroll
    for (int f = 0; f < 8; ++f)
#pragma unroll
        for (int j = 0; j < 4; ++j)
#pragma unroll
            for (int d = 0; d < 4; ++d) {
                int row_l = wmw + f * 16 + quad * 4 + d;
                int col_l = wnw + j * 16 + r;
                outKV[(size_t)(m0 + row_l) * H_ + ncol0 + col_l] =
                    fmaxf(acc[f][j][d], 0.0f);
            }

    // bf16 transposed writes via LDS, 2 chunks of 128 rows (CP=257)
    unsigned short* wsT = isKeys ? kT : vT;
    const int b  = m0 >> 10;
    const int s0 = m0 & 1023;
    unsigned short* dstB = wsT + (size_t)b * H_ * S_ + (size_t)ncol0 * S_ + s0;

#pragma unroll
    for (int ch = 0; ch < 2; ++ch) {
        if ((wave >> 2) == ch) {
#pragma unroll
            for (int f = 0; f < 8; ++f)
#pragma unroll
                for (int j = 0; j < 4; ++j)
#pragma unroll
                    for (int d = 0; d < 4; ++d) {
                        int lrow = f * 16 + quad * 4 + d;    // 0..127
                        int col  = wnw + j * 16 + r;         // 0..255
                        lds[lrow * CP + col] = f2bf(fmaxf(acc[f][j][d], 0.0f));
                    }
        }
        __syncthreads();
#pragma unroll
        for (int it = 0; it < 16; ++it) {
            int o   = it * 512 + tid;
            int n_l = o >> 5;                     // 0..255
            int m4  = (o & 31) * 4;               // 0..124
            ushort4 v;
            v.x = lds[(m4 + 0) * CP + n_l];
            v.y = lds[(m4 + 1) * CP + n_l];
            v.z = lds[(m4 + 2) * CP + n_l];
            v.w = lds[(m4 + 3) * CP + n_l];
            *(ushort4*)(dstB + (size_t)n_l * S_ + ch * 128 + m4) = v;
        }
        __syncthreads();
    }
}

// ---------------------------------------------------------------------------
// GEMM2 (batched): mem[b][m,n] = sum_t kT[b][m,t]*vT[b][n,t].
// Same 8-phase core. 256 blocks; XCD x owns batches {2x,2x+1}.
// ---------------------------------------------------------------------------
__global__ __launch_bounds__(512, 2) void gemm2_kernel(
    const unsigned short* __restrict__ kT, const unsigned short* __restrict__ vT,
    float* __restrict__ mem)
{
    __shared__ unsigned short lds[65536];         // 128 KiB

    const int tid  = threadIdx.x;
    const int wave = tid >> 6, lane = tid & 63;
    const int quad = lane >> 4, r = lane & 15;
    const int wmw  = (wave >> 2) * 128;
    const int wnw  = (wave & 3) * 64;

    const int L   = blockIdx.x;
    const int xcd = L & 7, s = L >> 3;            // s: 0..31
    const int b   = xcd * 2 + (s >> 4);           // batch
    const int tt  = s & 15;
    const int m0  = (tt >> 2) * BM;
    const int n0  = (tt & 3) * BN;

    const unsigned short* Ag = kT + (size_t)b * H_ * S_ + (size_t)m0 * S_;
    const unsigned short* Bg = vT + (size_t)b * H_ * S_ + (size_t)n0 * S_;

    floatx4 acc[8][4] = {};
    gemm_core(Ag, Bg, lds, acc, wave, lane);

    float* outb = mem + (size_t)b * H_ * H_;
#pragma unroll
    for (int f = 0; f < 8; ++f)
#pragma unroll
        for (int j = 0; j < 4; ++j)
#pragma unroll
            for (int d = 0; d < 4; ++d) {
                int row_l = wmw + f * 16 + quad * 4 + d;
                int col_l = wnw + j * 16 + r;
                outb[(size_t)(m0 + row_l) * H_ + n0 + col_l] = acc[f][j][d];
            }
}

extern "C" void kernel_launch(void* const* d_in, const int* in_sizes, int n_in,
                              void* d_out, int out_size, void* d_ws, size_t ws_size,
                              hipStream_t stream) {
    const float* x = (const float*)d_in[0];   // [16,1024,1024] f32
    const float* W = (const float*)d_in[1];   // [2048,1024] f32
    float* out = (float*)d_out;               // mem(16M) | keys(16M) | vals(16M) f32

    // Stash bf16 inputs in d_out's mem region (not written until gemm2)
    unsigned short* xb = (unsigned short*)d_out;            // 33.5 MB
    unsigned short* Wb = xb + (size_t)XN;                   //  4.2 MB (total 37.7 < 64 MB)

    // ws: keysT/valsT bf16 [B][H][S] (64 MB)
    unsigned short* kT = (unsigned short*)d_ws;
    unsigned short* vT = kT + (size_t)B_ * H_ * S_;

    convert_kernel<<<dim3((XN + WN) / 2048), dim3(256), 0, stream>>>(x, W, xb, Wb);

    gemm1_kernel<<<dim3(512), dim3(512), 0, stream>>>(xb, Wb, out, kT, vT);

    gemm2_kernel<<<dim3(256), dim3(512), 0, stream>>>(kT, vT, out);
}

// Round 9
// 356.169 us; speedup vs baseline: 1.0273x; 1.0028x over previous
//
#include <hip/hip_runtime.h>

// Problem constants
#define B_  16
#define S_  1024
#define IN_ 1024
#define H_  1024
#define N1  (2*H_)          // 2048 output cols of GEMM1
#define M1  (B_*S_)         // 16384 rows of GEMM1
#define K1  IN_             // 1024
#define XN  (M1*IN_)        // 16,777,216 elems of x
#define WN  (N1*IN_)        //  2,097,152 elems of W

// 256x256x64 8-wave tile, double-buffered split-K LDS, 8-phase schedule.
// THIS ROUND (vs r8, single change): conflict-free swizzle p^((row>>1)&3)
// (was p^(row&3), a 4-way bank conflict on every ds_read_b128 at 64-B rows).
#define BM  256
#define BN  256
#define BK  64
#define CP  257             // epilogue transpose LDS stride (odd -> conflict-free)

// LDS (shorts): per dbuf = A[kh=0][256][32] A[kh=1][256][32]
//                          B[kh=0][256][32] B[kh=1][256][32]  (64 KiB)
#define USZ  8192
#define ASZ  16384
#define TBUF 32768

typedef __attribute__((ext_vector_type(8))) short  short8;   // 8 bf16 (MFMA A/B frag)
typedef __attribute__((ext_vector_type(4))) float  floatx4;  // MFMA C/D frag

// fp32 -> bf16 round-to-nearest-even
__device__ __forceinline__ unsigned short f2bf(float f) {
    unsigned int u = __float_as_uint(f);
    u += 0x7fffu + ((u >> 16) & 1u);
    return (unsigned short)(u >> 16);
}

// async global->LDS, 16 B per lane; LDS dst is wave-uniform base + lane*16
#define GLDS16(gp, lp) __builtin_amdgcn_global_load_lds(                      \
    (const __attribute__((address_space(1))) void*)(gp),                      \
    (__attribute__((address_space(3))) void*)(lp), 16, 0, 0)

#define OPEN_VM6 { asm volatile("s_waitcnt vmcnt(6)" ::: "memory");           \
                   __builtin_amdgcn_s_barrier();                              \
                   __builtin_amdgcn_sched_barrier(0); }
#define OPEN_VM4 { asm volatile("s_waitcnt vmcnt(4)" ::: "memory");           \
                   __builtin_amdgcn_s_barrier();                              \
                   __builtin_amdgcn_sched_barrier(0); }
#define OPEN_VM0 { asm volatile("s_waitcnt vmcnt(0)" ::: "memory");           \
                   __builtin_amdgcn_s_barrier();                              \
                   __builtin_amdgcn_sched_barrier(0); }
#define OPEN_BAR { __builtin_amdgcn_s_barrier();                              \
                   __builtin_amdgcn_sched_barrier(0); }
#define CLOSE_BAR { __builtin_amdgcn_sched_barrier(0);                        \
                    __builtin_amdgcn_s_barrier(); }
#define LGKM0 { asm volatile("s_waitcnt lgkmcnt(0)" ::: "memory");            \
                __builtin_amdgcn_sched_barrier(0); }

// ---------------------------------------------------------------------------
// convert: fp32 -> bf16 for x and W (memory-bound).
// ---------------------------------------------------------------------------
__global__ __launch_bounds__(256) void convert_kernel(
    const float* __restrict__ x, const float* __restrict__ W,
    unsigned short* __restrict__ xb, unsigned short* __restrict__ Wb)
{
    size_t i = ((size_t)blockIdx.x * 256 + threadIdx.x) * 8;
    const float* src;
    unsigned short* dst;
    if (i < (size_t)XN) { src = x + i; dst = xb + i; }
    else                { src = W + (i - XN); dst = Wb + (i - XN); }
    float4 a = *(const float4*)(src);
    float4 b = *(const float4*)(src + 4);
    ushort4 p = { f2bf(a.x), f2bf(a.y), f2bf(a.z), f2bf(a.w) };
    ushort4 q = { f2bf(b.x), f2bf(b.y), f2bf(b.z), f2bf(b.w) };
    *(ushort4*)(dst)     = p;
    *(ushort4*)(dst + 4) = q;
}

// ---------------------------------------------------------------------------
// Stage one 16 KiB unit (op: 0=A 1=B, kh: k-half) of K-tile at kt into buf.
// Swizzle on GLOBAL source: phys chunk p at row holds logical
// c = p ^ ((row>>1)&3)  [conflict-free: 16-lane cycle-group slot-id
// (4r + ((r>>1)&3)) mod 8 covers all 8 slots over r=0..7 -> exact 2-way].
// LDS dest linear (global_load_lds constraint). 2 glds/thread.
// ---------------------------------------------------------------------------
__device__ __forceinline__ void stage_u(
    const unsigned short* Ag, const unsigned short* Bg,
    unsigned short* buf, int op, int kh, int kt, int wave, int lane)
{
    const unsigned short* src = op ? Bg : Ag;
    unsigned short* dst = buf + op * ASZ + kh * USZ;
#pragma unroll
    for (int h = 0; h < 2; ++h) {
        int e   = (wave * 2 + h) * 64 + lane;     // chunk id 0..1023 in unit
        int row = e >> 2, p = e & 3;
        int c   = p ^ ((row >> 1) & 3);           // conflict-free swizzle
        GLDS16(src + (size_t)row * 1024 + kt + kh * 32 + c * 8,
               dst + (wave * 2 + h) * 512);
    }
}

// ---------------------------------------------------------------------------
// 8-phase K-loop core. Wave tile 128x64 (8 waves: 2 wave-rows x 4 wave-cols).
// Phase (T, q): q=(kh<<1)|mh. B frags read at mh==0, reused at mh==1.
// Reader slot = quad ^ ((r>>1)&3): conflict-free (see stage_u).
// ---------------------------------------------------------------------------
__device__ __forceinline__ void gemm_core(
    const unsigned short* Ag, const unsigned short* Bg,
    unsigned short* lds, floatx4 (&acc)[8][4], int wave, int lane)
{
    const int quad = lane >> 4, r = lane & 15;
    const int wmw  = (wave >> 2) * 128;
    const int wnw  = (wave & 3) * 64;
    const int sw   = (quad ^ ((r >> 1) & 3)) * 8; // conflict-free read slot

    short8 af[4], bfr[4];

#define READ_B(cur_, kh_)                                                     \
    _Pragma("unroll") for (int j = 0; j < 4; ++j)                             \
        bfr[j] = *(const short8*)((cur_) + ASZ + (kh_) * USZ                  \
                                  + (wnw + j * 16 + r) * 32 + sw);
#define READ_A(cur_, kh_, mh_)                                                \
    _Pragma("unroll") for (int i = 0; i < 4; ++i)                             \
        af[i] = *(const short8*)((cur_) + (kh_) * USZ                         \
                                 + (wmw + ((mh_) * 4 + i) * 16 + r) * 32 + sw);
#define MFMA16(mh_)                                                           \
    __builtin_amdgcn_s_setprio(1);                                            \
    _Pragma("unroll") for (int i = 0; i < 4; ++i)                             \
        _Pragma("unroll") for (int j = 0; j < 4; ++j)                         \
            acc[(mh_) * 4 + i][j] = __builtin_amdgcn_mfma_f32_16x16x32_bf16(  \
                af[i], bfr[j], acc[(mh_) * 4 + i][j], 0, 0, 0);               \
    __builtin_amdgcn_s_setprio(0);

    // Prologue: tile 0 only (8 glds); tile T+1 staged during tile T.
    stage_u(Ag, Bg, lds, 0, 0, 0, wave, lane);
    stage_u(Ag, Bg, lds, 1, 0, 0, wave, lane);
    stage_u(Ag, Bg, lds, 0, 1, 0, wave, lane);
    stage_u(Ag, Bg, lds, 1, 1, 0, wave, lane);

    for (int T = 0; T < 15; ++T) {
        unsigned short* cur = lds + (T & 1) * TBUF;
        unsigned short* nxt = lds + ((T + 1) & 1) * TBUF;
        const int ktn = (T + 1) * BK;
        // q=0: kh=0, mh=0   (vmcnt(6): drain tile T k0-units, keep 6 newer)
        stage_u(Ag, Bg, nxt, 0, 0, ktn, wave, lane);
        OPEN_VM6
        READ_B(cur, 0) READ_A(cur, 0, 0)
        LGKM0
        MFMA16(0)
        CLOSE_BAR
        // q=1: kh=0, mh=1
        stage_u(Ag, Bg, nxt, 1, 0, ktn, wave, lane);
        OPEN_BAR
        READ_A(cur, 0, 1)
        LGKM0
        MFMA16(1)
        CLOSE_BAR
        // q=2: kh=1, mh=0   (vmcnt(6): drain tile T k1-units)
        stage_u(Ag, Bg, nxt, 0, 1, ktn, wave, lane);
        OPEN_VM6
        READ_B(cur, 1) READ_A(cur, 1, 0)
        LGKM0
        MFMA16(0)
        CLOSE_BAR
        // q=3: kh=1, mh=1
        stage_u(Ag, Bg, nxt, 1, 1, ktn, wave, lane);
        OPEN_BAR
        READ_A(cur, 1, 1)
        LGKM0
        MFMA16(1)
        CLOSE_BAR
    }
    {   // Peeled tile 15: no staging; drain 4 -> 0.
        unsigned short* cur = lds + TBUF;
        OPEN_VM4
        READ_B(cur, 0) READ_A(cur, 0, 0)
        LGKM0
        MFMA16(0)
        CLOSE_BAR
        OPEN_BAR
        READ_A(cur, 0, 1)
        LGKM0
        MFMA16(1)
        CLOSE_BAR
        OPEN_VM0
        READ_B(cur, 1) READ_A(cur, 1, 0)
        LGKM0
        MFMA16(0)
        CLOSE_BAR
        OPEN_BAR
        READ_A(cur, 1, 1)
        LGKM0
        MFMA16(1)
    }
    __syncthreads();                              // LDS reusable by epilogue
#undef READ_B
#undef READ_A
#undef MFMA16
}

// ---------------------------------------------------------------------------
// GEMM1: C[m,n] = sum_k xb[m,k]*Wb[n,k]; relu -> fp32 keys/vals to d_out and
// bf16 transposed keysT/valsT to ws. 512 blocks; XCD x owns m-stripe
// [8x,8x+8) x all 8 n-tiles.
// ---------------------------------------------------------------------------
__global__ __launch_bounds__(512, 2) void gemm1_kernel(
    const unsigned short* __restrict__ xb, const unsigned short* __restrict__ Wb,
    float* __restrict__ out,
    unsigned short* __restrict__ kT, unsigned short* __restrict__ vT)
{
    __shared__ unsigned short lds[65536];         // 128 KiB

    const int tid  = threadIdx.x;
    const int wave = tid >> 6, lane = tid & 63;
    const int quad = lane >> 4, r = lane & 15;
    const int wmw  = (wave >> 2) * 128;
    const int wnw  = (wave & 3) * 64;

    const int L   = blockIdx.x;
    const int xcd = L & 7, s = L >> 3;            // s: 0..63
    const int mt  = xcd * 8 + (s >> 3);           // 0..63
    const int nt  = s & 7;                        // 0..7
    const int m0  = mt * BM, n0 = nt * BN;

    const unsigned short* Ag = xb + (size_t)m0 * K1;
    const unsigned short* Bg = Wb + (size_t)n0 * K1;

    floatx4 acc[8][4] = {};
    gemm_core(Ag, Bg, lds, acc, wave, lane);

    const bool isKeys = (nt < 4);
    float* outKV    = out + (isKeys ? (size_t)M1 * H_ : (size_t)2 * M1 * H_);
    const int ncol0 = isKeys ? n0 : (n0 - 1024);

    // fp32 relu writes (each wave its own 128x64 region)
#pragma unroll
    for (int f = 0; f < 8; ++f)
#pragma unroll
        for (int j = 0; j < 4; ++j)
#pragma unroll
            for (int d = 0; d < 4; ++d) {
                int row_l = wmw + f * 16 + quad * 4 + d;
                int col_l = wnw + j * 16 + r;
                outKV[(size_t)(m0 + row_l) * H_ + ncol0 + col_l] =
                    fmaxf(acc[f][j][d], 0.0f);
            }

    // bf16 transposed writes via LDS, 2 chunks of 128 rows (CP=257)
    unsigned short* wsT = isKeys ? kT : vT;
    const int b  = m0 >> 10;
    const int s0 = m0 & 1023;
    unsigned short* dstB = wsT + (size_t)b * H_ * S_ + (size_t)ncol0 * S_ + s0;

#pragma unroll
    for (int ch = 0; ch < 2; ++ch) {
        if ((wave >> 2) == ch) {
#pragma unroll
            for (int f = 0; f < 8; ++f)
#pragma unroll
                for (int j = 0; j < 4; ++j)
#pragma unroll
                    for (int d = 0; d < 4; ++d) {
                        int lrow = f * 16 + quad * 4 + d;    // 0..127
                        int col  = wnw + j * 16 + r;         // 0..255
                        lds[lrow * CP + col] = f2bf(fmaxf(acc[f][j][d], 0.0f));
                    }
        }
        __syncthreads();
#pragma unroll
        for (int it = 0; it < 16; ++it) {
            int o   = it * 512 + tid;
            int n_l = o >> 5;                     // 0..255
            int m4  = (o & 31) * 4;               // 0..124
            ushort4 v;
            v.x = lds[(m4 + 0) * CP + n_l];
            v.y = lds[(m4 + 1) * CP + n_l];
            v.z = lds[(m4 + 2) * CP + n_l];
            v.w = lds[(m4 + 3) * CP + n_l];
            *(ushort4*)(dstB + (size_t)n_l * S_ + ch * 128 + m4) = v;
        }
        __syncthreads();
    }
}

// ---------------------------------------------------------------------------
// GEMM2 (batched): mem[b][m,n] = sum_t kT[b][m,t]*vT[b][n,t].
// Same 8-phase core. 256 blocks; XCD x owns batches {2x,2x+1}.
// ---------------------------------------------------------------------------
__global__ __launch_bounds__(512, 2) void gemm2_kernel(
    const unsigned short* __restrict__ kT, const unsigned short* __restrict__ vT,
    float* __restrict__ mem)
{
    __shared__ unsigned short lds[65536];         // 128 KiB

    const int tid  = threadIdx.x;
    const int wave = tid >> 6, lane = tid & 63;
    const int quad = lane >> 4, r = lane & 15;
    const int wmw  = (wave >> 2) * 128;
    const int wnw  = (wave & 3) * 64;

    const int L   = blockIdx.x;
    const int xcd = L & 7, s = L >> 3;            // s: 0..31
    const int b   = xcd * 2 + (s >> 4);           // batch
    const int tt  = s & 15;
    const int m0  = (tt >> 2) * BM;
    const int n0  = (tt & 3) * BN;

    const unsigned short* Ag = kT + (size_t)b * H_ * S_ + (size_t)m0 * S_;
    const unsigned short* Bg = vT + (size_t)b * H_ * S_ + (size_t)n0 * S_;

    floatx4 acc[8][4] = {};
    gemm_core(Ag, Bg, lds, acc, wave, lane);

    float* outb = mem + (size_t)b * H_ * H_;
#pragma unroll
    for (int f = 0; f < 8; ++f)
#pragma unroll
        for (int j = 0; j < 4; ++j)
#pragma unroll
            for (int d = 0; d < 4; ++d) {
                int row_l = wmw + f * 16 + quad * 4 + d;
                int col_l = wnw + j * 16 + r;
                outb[(size_t)(m0 + row_l) * H_ + n0 + col_l] = acc[f][j][d];
            }
}

extern "C" void kernel_launch(void* const* d_in, const int* in_sizes, int n_in,
                              void* d_out, int out_size, void* d_ws, size_t ws_size,
                              hipStream_t stream) {
    const float* x = (const float*)d_in[0];   // [16,1024,1024] f32
    const float* W = (const float*)d_in[1];   // [2048,1024] f32
    float* out = (float*)d_out;               // mem(16M) | keys(16M) | vals(16M) f32

    // Stash bf16 inputs in d_out's mem region (not written until gemm2)
    unsigned short* xb = (unsigned short*)d_out;            // 33.5 MB
    unsigned short* Wb = xb + (size_t)XN;                   //  4.2 MB (total 37.7 < 64 MB)

    // ws: keysT/valsT bf16 [B][H][S] (64 MB)
    unsigned short* kT = (unsigned short*)d_ws;
    unsigned short* vT = kT + (size_t)B_ * H_ * S_;

    convert_kernel<<<dim3((XN + WN) / 2048), dim3(256), 0, stream>>>(x, W, xb, Wb);

    gemm1_kernel<<<dim3(512), dim3(512), 0, stream>>>(xb, Wb, out, kT, vT);

    gemm2_kernel<<<dim3(256), dim3(512), 0, stream>>>(kT, vT, out);
}